// Round 5
// baseline (462.457 us; speedup 1.0000x reference)
//
#include <hip/hip_runtime.h>
#include <hip/hip_fp16.h>

#define NN 100000
#define WIN 12500          // dst nodes per bucket (8 buckets)
#define CAP 204800         // edge capacity per bucket
#define EPB 16             // edges per thread in phase A
#define NSL 32             // ownership slices per bucket
#define WPS 391            // dst nodes per slice (ceil(WIN/NSL))

typedef _Float16 f16;
typedef _Float16 f16x8 __attribute__((ext_vector_type(8)));
typedef float f32x4 __attribute__((ext_vector_type(4)));

// ---------------------------------------------------------------------------
// Edge index may arrive as int32 or int64; detect via odd 32-bit words == 0.
// ---------------------------------------------------------------------------
__device__ __forceinline__ int eload(const void* e, long i, int is64) {
  if (is64) return (int)((const long long*)e)[i];
  return ((const int*)e)[i];
}

__global__ __launch_bounds__(1024) void k_detect(const unsigned* __restrict__ e,
                                                 int* __restrict__ flag) {
  __shared__ unsigned red[1024];
  int t = threadIdx.x;
  unsigned acc = e[1 + 2 * t] | e[1 + 2 * t + 2048];
  red[t] = acc;
  __syncthreads();
  for (int off = 512; off > 0; off >>= 1) {
    if (t < off) red[t] |= red[t + off];
    __syncthreads();
  }
  if (t == 0) *flag = (red[0] == 0) ? 1 : 0;  // 1 => int64
}

__global__ void k_init8(int* __restrict__ bcur) {
  int i = threadIdx.x;
  if (i < 8) bcur[i] = i * CAP;
}

// ---------------------------------------------------------------------------
// Phase A: multi-split edges into 8 dst-range buckets (SoA: srcb/dstb),
// coalesced-run writes; one global atomicAdd per bucket per block.
// ---------------------------------------------------------------------------
__global__ __launch_bounds__(256) void k_bucket(const void* __restrict__ e,
                                                const int* __restrict__ flag,
                                                int E, int* __restrict__ bcur,
                                                int* __restrict__ srcb,
                                                int* __restrict__ dstb) {
  __shared__ unsigned long long sA[256], sB[256];
  __shared__ int bases[8];
  const int tid = threadIdx.x;
  const long base = (long)blockIdx.x * (256 * EPB);
  const int is64 = *flag;

  int sv[EPB], dv[EPB];
  unsigned long long c01 = 0, c23 = 0;
#pragma unroll
  for (int j = 0; j < EPB; ++j) {
    long idx = base + j * 256 + tid;
    int s = 0, d = -1;
    if (idx < E) {
      s = eload(e, idx, is64);
      d = eload(e, (long)E + idx, is64);
    }
    sv[j] = s; dv[j] = d;
    if (d >= 0) {
      int b = (unsigned)d / WIN;
      if (b < 4) c01 += 1ull << (16 * b);
      else       c23 += 1ull << (16 * (b - 4));
    }
  }
  sA[tid] = c01; sB[tid] = c23;
  __syncthreads();
  for (int off = 1; off < 256; off <<= 1) {
    unsigned long long a = (tid >= off) ? sA[tid - off] : 0;
    unsigned long long b = (tid >= off) ? sB[tid - off] : 0;
    __syncthreads();
    sA[tid] += a; sB[tid] += b;
    __syncthreads();
  }
  const unsigned long long eA = sA[tid] - c01;
  const unsigned long long eB = sB[tid] - c23;
  if (tid == 0) {
    unsigned long long tA = sA[255], tB = sB[255];
#pragma unroll
    for (int b = 0; b < 4; ++b)
      bases[b] = atomicAdd(&bcur[b], (int)((tA >> (16 * b)) & 0xffff));
#pragma unroll
    for (int b = 4; b < 8; ++b)
      bases[b] = atomicAdd(&bcur[b], (int)((tB >> (16 * (b - 4))) & 0xffff));
  }
  __syncthreads();

  unsigned long long r01 = 0, r23 = 0;
#pragma unroll
  for (int j = 0; j < EPB; ++j) {
    int d = dv[j];
    if (d < 0) continue;
    int b = (unsigned)d / WIN;
    int off;
    if (b < 4) {
      int sh = 16 * b;
      off = (int)(((eA + r01) >> sh) & 0xffff);
      r01 += 1ull << sh;
    } else {
      int sh = 16 * (b - 4);
      off = (int)(((eB + r23) >> sh) & 0xffff);
      r23 += 1ull << sh;
    }
    int pos = bases[b] + off;
    srcb[pos] = sv[j];
    dstb[pos] = d;
  }
}

// ---------------------------------------------------------------------------
// Ownership histogram: block (bucket w = blockIdx&7, slice = blockIdx>>3)
// owns dst window [nlo,nhi); LDS counts; exclusive => plain stores, no zeroing.
// ---------------------------------------------------------------------------
__global__ __launch_bounds__(512) void k_hist_o(const int* __restrict__ dstb,
                                                const int* __restrict__ bcur,
                                                int* __restrict__ counts) {
  __shared__ int lc[WPS];
  const int w = blockIdx.x & 7;
  const int sl = blockIdx.x >> 3;
  const int nlo = w * WIN + sl * WPS;
  const int whi = (w + 1) * WIN;
  const int nhi = (nlo + WPS < whi) ? nlo + WPS : whi;
  const int nw = nhi - nlo;
  for (int j = threadIdx.x; j < nw; j += 512) lc[j] = 0;
  __syncthreads();
  const int cnt = bcur[w] - w * CAP;
  const long b0 = (long)w * CAP;
  for (long i = b0 + threadIdx.x; i < b0 + cnt; i += 512) {
    int d = dstb[i];
    if (d >= nlo && d < nhi) atomicAdd(&lc[d - nlo], 1);
  }
  __syncthreads();
  for (int j = threadIdx.x; j < nw; j += 512) counts[nlo + j] = lc[j];
}

// ---------------------------------------------------------------------------
// Ownership scatter: LDS cursors from rowptr; owned edges write src into the
// block's ~25KB contiguous csr window (lines fill fully in L2).
// ---------------------------------------------------------------------------
__global__ __launch_bounds__(512) void k_scatter_o(const int* __restrict__ dstb,
                                                   const int* __restrict__ srcb,
                                                   const int* __restrict__ bcur,
                                                   const int* __restrict__ rowptr,
                                                   int* __restrict__ csr) {
  __shared__ int cur[WPS];
  const int w = blockIdx.x & 7;
  const int sl = blockIdx.x >> 3;
  const int nlo = w * WIN + sl * WPS;
  const int whi = (w + 1) * WIN;
  const int nhi = (nlo + WPS < whi) ? nlo + WPS : whi;
  const int nw = nhi - nlo;
  for (int j = threadIdx.x; j < nw; j += 512) cur[j] = rowptr[nlo + j];
  __syncthreads();
  const int cnt = bcur[w] - w * CAP;
  const long b0 = (long)w * CAP;
  for (long i = b0 + threadIdx.x; i < b0 + cnt; i += 512) {
    int d = dstb[i];
    if (d >= nlo && d < nhi) {
      int pos = atomicAdd(&cur[d - nlo], 1);
      csr[pos] = srcb[i];
    }
  }
}

__global__ void k_dinv(const int* __restrict__ counts, float* __restrict__ dinv) {
  int i = blockIdx.x * 256 + threadIdx.x;
  if (i < NN) dinv[i] = rsqrtf((float)counts[i] + 1.0f);  // +1 self-loop
}

// ---- 3-kernel exclusive scan of counts[NN] -> rowptr ----------------------
__global__ __launch_bounds__(512) void k_scan1(const int* __restrict__ counts,
                                               int* __restrict__ rowptr,
                                               int* __restrict__ bsum) {
  __shared__ int sm[512];
  int tid = threadIdx.x;
  int i = blockIdx.x * 512 + tid;
  int v = (i < NN) ? counts[i] : 0;
  sm[tid] = v;
  __syncthreads();
  for (int off = 1; off < 512; off <<= 1) {
    int t = (tid >= off) ? sm[tid - off] : 0;
    __syncthreads();
    sm[tid] += t;
    __syncthreads();
  }
  if (i < NN) rowptr[i] = sm[tid] - v;
  if (tid == 511) bsum[blockIdx.x] = sm[tid];
}

__global__ void k_scan2(int* __restrict__ bsum, int nb) {
  if (threadIdx.x == 0 && blockIdx.x == 0) {
    int run = 0;
    for (int b = 0; b < nb; ++b) { int v = bsum[b]; bsum[b] = run; run += v; }
  }
}

__global__ __launch_bounds__(512) void k_scan3(int* __restrict__ rowptr,
                                               const int* __restrict__ bsum, int E) {
  int i = blockIdx.x * 512 + threadIdx.x;
  if (i < NN) rowptr[i] += bsum[blockIdx.x];
  if (i == 0) rowptr[NN] = E;
}

// ---------------------------------------------------------------------------
// W prep: Wt[n][k] fp16 from W[k][n] fp32.
// ---------------------------------------------------------------------------
template <int COUT>
__global__ void k_wprep(const float* __restrict__ W, f16* __restrict__ Wt) {
  int idx = blockIdx.x * 256 + threadIdx.x;
  if (idx < 128 * COUT) {
    int k = idx / COUT, n = idx % COUT;
    Wt[n * 128 + k] = (f16)W[idx];
  }
}

// ---------------------------------------------------------------------------
// MFMA GEMM: hn[row] = ((relu?)X[row] @ W) * dinv[row], fp16 out.
// ---------------------------------------------------------------------------
template <int COUT, bool RELU, typename TIN>
__global__ __launch_bounds__(256) void gemm_mfma(const TIN* __restrict__ X,
                                                 const f16* __restrict__ Wt,
                                                 const float* __restrict__ dinv,
                                                 f16* __restrict__ Y) {
  constexpr int NF = COUT / 16;
  __shared__ f16 Al[128 * 128];
  __shared__ f16 Bl[COUT * 128];
  const int tid = threadIdx.x;
  const long row0 = (long)blockIdx.x * 128;

  for (int c = tid; c < COUT * 16; c += 256) {
    int n = c >> 4, g = c & 15;
    f16x8 v = *(const f16x8*)&Wt[n * 128 + g * 8];
    *(f16x8*)((char*)Bl + n * 256 + ((g * 16) ^ ((n & 7) << 4))) = v;
  }
  for (int c = tid; c < 2048; c += 256) {
    int r = c >> 4, g = c & 15;
    long grow = row0 + r;
    f16x8 v;
    if (grow < NN) {
      if constexpr (sizeof(TIN) == 4) {
        const float4* p = (const float4*)&X[grow * 128 + g * 8];
        float4 p0 = p[0], p1 = p[1];
        float f[8] = {p0.x, p0.y, p0.z, p0.w, p1.x, p1.y, p1.z, p1.w};
#pragma unroll
        for (int j = 0; j < 8; ++j) {
          float t = RELU ? fmaxf(f[j], 0.f) : f[j];
          v[j] = (f16)t;
        }
      } else {
        v = *(const f16x8*)&X[grow * 128 + g * 8];
        if (RELU) {
#pragma unroll
          for (int j = 0; j < 8; ++j) v[j] = v[j] > (f16)0 ? v[j] : (f16)0;
        }
      }
    } else {
#pragma unroll
      for (int j = 0; j < 8; ++j) v[j] = (f16)0;
    }
    *(f16x8*)((char*)Al + r * 256 + ((g * 16) ^ ((r & 7) << 4))) = v;
  }
  __syncthreads();

  const int l = tid & 63, w = tid >> 6;
  const int lm = l & 15, lg = l >> 4;
  const int r0 = w * 32 + lm, r1 = r0 + 16;

  f32x4 acc0[NF], acc1[NF];
#pragma unroll
  for (int nf = 0; nf < NF; ++nf) {
    acc0[nf] = (f32x4)(0.f);
    acc1[nf] = (f32x4)(0.f);
  }

#pragma unroll
  for (int kk = 0; kk < 4; ++kk) {
    const int kb = kk * 64 + lg * 16;
    f16x8 a0 = *(const f16x8*)((const char*)Al + r0 * 256 + (kb ^ ((r0 & 7) << 4)));
    f16x8 a1 = *(const f16x8*)((const char*)Al + r1 * 256 + (kb ^ ((r1 & 7) << 4)));
#pragma unroll
    for (int nf = 0; nf < NF; ++nf) {
      int n = nf * 16 + lm;
      f16x8 b = *(const f16x8*)((const char*)Bl + n * 256 + (kb ^ ((n & 7) << 4)));
      acc0[nf] = __builtin_amdgcn_mfma_f32_16x16x32_f16(a0, b, acc0[nf], 0, 0, 0);
      acc1[nf] = __builtin_amdgcn_mfma_f32_16x16x32_f16(a1, b, acc1[nf], 0, 0, 0);
    }
  }

#pragma unroll
  for (int reg = 0; reg < 4; ++reg) {
    long gr0 = row0 + w * 32 + lg * 4 + reg;
    long gr1 = gr0 + 16;
    float d0 = (gr0 < NN) ? dinv[gr0] : 0.f;
    float d1 = (gr1 < NN) ? dinv[gr1] : 0.f;
#pragma unroll
    for (int nf = 0; nf < NF; ++nf) {
      if (gr0 < NN) Y[gr0 * COUT + nf * 16 + lm] = (f16)(acc0[nf][reg] * d0);
      if (gr1 < NN) Y[gr1 * COUT + nf * 16 + lm] = (f16)(acc1[nf][reg] * d1);
    }
  }
}

// ---------------------------------------------------------------------------
// Gather: out[d] = dinv[d]*(hn[d] + sum_{s in N(d)} hn[s]) + bias.
// ---------------------------------------------------------------------------
template <int C, typename TOUT>
__global__ __launch_bounds__(256) void k_agg_csr(const __half* __restrict__ hn,
                                                 const int* __restrict__ rowptr,
                                                 const int* __restrict__ csr,
                                                 const float* __restrict__ dinv,
                                                 const float* __restrict__ bias,
                                                 TOUT* __restrict__ out) {
  constexpr int TP = C / 8;
  long t = (long)blockIdx.x * 256 + threadIdx.x;
  int d = (int)(t / TP);
  if (d >= NN) return;
  int c8 = (int)(t % TP) * 8;

  float acc[8];
  {
    float4 raw = *(const float4*)&hn[(long)d * C + c8];
    const __half2* h2 = (const __half2*)&raw;
#pragma unroll
    for (int q = 0; q < 4; ++q) {
      float2 f = __half22float2(h2[q]);
      acc[2 * q] = f.x; acc[2 * q + 1] = f.y;
    }
  }
  int e = rowptr[d];
  const int end = rowptr[d + 1];

  for (; e + 4 <= end; e += 4) {
    int s0 = csr[e], s1 = csr[e + 1], s2 = csr[e + 2], s3 = csr[e + 3];
    float4 r0 = *(const float4*)&hn[(long)s0 * C + c8];
    float4 r1 = *(const float4*)&hn[(long)s1 * C + c8];
    float4 r2 = *(const float4*)&hn[(long)s2 * C + c8];
    float4 r3 = *(const float4*)&hn[(long)s3 * C + c8];
    const __half2* a0 = (const __half2*)&r0;
    const __half2* a1 = (const __half2*)&r1;
    const __half2* a2 = (const __half2*)&r2;
    const __half2* a3 = (const __half2*)&r3;
#pragma unroll
    for (int q = 0; q < 4; ++q) {
      float2 f0 = __half22float2(a0[q]);
      float2 f1 = __half22float2(a1[q]);
      float2 f2 = __half22float2(a2[q]);
      float2 f3 = __half22float2(a3[q]);
      acc[2 * q]     += (f0.x + f1.x) + (f2.x + f3.x);
      acc[2 * q + 1] += (f0.y + f1.y) + (f2.y + f3.y);
    }
  }
  for (; e < end; ++e) {
    int s = csr[e];
    float4 r0 = *(const float4*)&hn[(long)s * C + c8];
    const __half2* a0 = (const __half2*)&r0;
#pragma unroll
    for (int q = 0; q < 4; ++q) {
      float2 f0 = __half22float2(a0[q]);
      acc[2 * q] += f0.x; acc[2 * q + 1] += f0.y;
    }
  }

  float dd = dinv[d];
  float4 b0 = *(const float4*)&bias[c8];
  float4 b1 = *(const float4*)&bias[c8 + 4];
  float o[8];
  o[0] = acc[0] * dd + b0.x; o[1] = acc[1] * dd + b0.y;
  o[2] = acc[2] * dd + b0.z; o[3] = acc[3] * dd + b0.w;
  o[4] = acc[4] * dd + b1.x; o[5] = acc[5] * dd + b1.y;
  o[6] = acc[6] * dd + b1.z; o[7] = acc[7] * dd + b1.w;

  if constexpr (sizeof(TOUT) == 2) {
    __half2 hp[4];
    hp[0] = __floats2half2_rn(o[0], o[1]);
    hp[1] = __floats2half2_rn(o[2], o[3]);
    hp[2] = __floats2half2_rn(o[4], o[5]);
    hp[3] = __floats2half2_rn(o[6], o[7]);
    *(float4*)&out[(long)d * C + c8] = *(float4*)hp;
  } else {
    *(float4*)&out[(long)d * C + c8]     = make_float4(o[0], o[1], o[2], o[3]);
    *(float4*)&out[(long)d * C + c8 + 4] = make_float4(o[4], o[5], o[6], o[7]);
  }
}

extern "C" void kernel_launch(void* const* d_in, const int* in_sizes, int n_in,
                              void* d_out, int out_size, void* d_ws, size_t ws_size,
                              hipStream_t stream) {
  const float* x  = (const float*)d_in[0];
  const void*  ep = d_in[1];
  const float* W1 = (const float*)d_in[2];
  const float* b1 = (const float*)d_in[3];
  const float* W2 = (const float*)d_in[4];
  const float* b2 = (const float*)d_in[5];
  float* out = (float*)d_out;
  const int E = in_sizes[1] / 2;

  // workspace layout (int-element offsets from base)
  float*  wsf    = (float*)d_ws;
  int*    wsi    = (int*)d_ws;
  int*    flag   = wsi;                        // [0]
  int*    bcur   = wsi + 16;                   // 8
  float*  dinv   = wsf + 64;                   // 100000 f
  int*    counts = wsi + 100096;               // 100000
  int*    rowptr = wsi + 200128;               // 100001
  int*    bsum   = wsi + 300160;               // 256
  int*    csr    = wsi + 300416;               // 1600000
  int*    srcb   = wsi + 1900416;              // 8*CAP
  int*    dstb   = wsi + 3538816;              // 8*CAP
  f16*    Wt1    = (f16*)(wsi + 5177216);      // 16384 halves
  f16*    Wt2    = (f16*)(wsi + 5185408);      // 8192 halves
  f16*    hn1    = (f16*)(wsi + 5189504);      // 12.8M halves
  f16*    a1     = (f16*)(wsi + 11589504);     // 12.8M halves
  f16*    hn2    = hn1;                        // hn1 dead once a1 built

  const int NB = (NN + 511) / 512;             // 196
  const int ABLK = (E + 256 * EPB - 1) / (256 * EPB);
  const int GB = (NN + 127) / 128;             // 782

  k_detect<<<1, 1024, 0, stream>>>((const unsigned*)ep, flag);
  k_init8<<<1, 64, 0, stream>>>(bcur);
  k_wprep<128><<<64, 256, 0, stream>>>(W1, Wt1);
  k_wprep<64><<<32, 256, 0, stream>>>(W2, Wt2);
  k_bucket<<<ABLK, 256, 0, stream>>>(ep, flag, E, bcur, srcb, dstb);
  k_hist_o<<<8 * NSL, 512, 0, stream>>>(dstb, bcur, counts);
  k_dinv<<<(NN + 255) / 256, 256, 0, stream>>>(counts, dinv);
  k_scan1<<<NB, 512, 0, stream>>>(counts, rowptr, bsum);
  k_scan2<<<1, 64, 0, stream>>>(bsum, NB);
  k_scan3<<<NB, 512, 0, stream>>>(rowptr, bsum, E);
  k_scatter_o<<<8 * NSL, 512, 0, stream>>>(dstb, srcb, bcur, rowptr, csr);

  // layer 1
  gemm_mfma<128, false, float><<<GB, 256, 0, stream>>>(x, Wt1, dinv, hn1);
  k_agg_csr<128, __half><<<(NN * 16) / 256, 256, 0, stream>>>(
      (const __half*)hn1, rowptr, csr, dinv, b1, (__half*)a1);

  // layer 2 (relu fused into staging conversion)
  gemm_mfma<64, true, f16><<<GB, 256, 0, stream>>>(a1, Wt2, dinv, hn2);
  k_agg_csr<64, float><<<(NN * 8) / 256, 256, 0, stream>>>(
      (const __half*)hn2, rowptr, csr, dinv, b2, out);
}

// Round 6
// 225.491 us; speedup vs baseline: 2.0509x; 2.0509x over previous
//
#include <hip/hip_runtime.h>
#include <hip/hip_fp16.h>

#define NN 100000
#define NSB 256            // dst windows (one ownership block each)
#define WPS2 391           // dst nodes per window (ceil(NN/NSB))
#define CAP2 8192          // edge capacity per window (mean 6256, sigma 79)
#define EPB 16             // edges per thread in split

typedef _Float16 f16;
typedef _Float16 f16x8 __attribute__((ext_vector_type(8)));
typedef float f32x4 __attribute__((ext_vector_type(4)));

// ---------------------------------------------------------------------------
// Edge index may arrive as int32 or int64; detect via odd 32-bit words == 0.
// ---------------------------------------------------------------------------
__device__ __forceinline__ int eload(const void* e, long i, int is64) {
  if (is64) return (int)((const long long*)e)[i];
  return ((const int*)e)[i];
}

__global__ __launch_bounds__(1024) void k_detect(const unsigned* __restrict__ e,
                                                 int* __restrict__ flag) {
  __shared__ unsigned red[1024];
  int t = threadIdx.x;
  unsigned acc = e[1 + 2 * t] | e[1 + 2 * t + 2048];
  red[t] = acc;
  __syncthreads();
  for (int off = 512; off > 0; off >>= 1) {
    if (t < off) red[t] |= red[t + off];
    __syncthreads();
  }
  if (t == 0) *flag = (red[0] == 0) ? 1 : 0;  // 1 => int64
}

__global__ void k_init256(int* __restrict__ bcur2) {
  int i = threadIdx.x;
  bcur2[i] = i * CAP2;
}

// ---------------------------------------------------------------------------
// 256-way multi-split by dst window. Per-block LDS hist (atomics), one global
// atomicAdd per window per block for run allocation, LDS-cursor replay.
// Runs are contiguous per window -> L2 lines fill completely before writeback.
// ---------------------------------------------------------------------------
__global__ __launch_bounds__(256) void k_split(const void* __restrict__ e,
                                               const int* __restrict__ flag,
                                               int E, int* __restrict__ bcur2,
                                               int* __restrict__ srcb,
                                               int* __restrict__ dstb) {
  __shared__ int hist[NSB];
  const int tid = threadIdx.x;
  const long b0 = (long)blockIdx.x * (256 * EPB);
  const int is64 = *flag;
  hist[tid] = 0;
  __syncthreads();

  int sv[EPB], dv[EPB];
#pragma unroll
  for (int j = 0; j < EPB; ++j) {
    long idx = b0 + j * 256 + tid;
    int s = 0, d = -1;
    if (idx < E) {
      s = eload(e, idx, is64);
      d = eload(e, (long)E + idx, is64);
    }
    sv[j] = s; dv[j] = d;
    if (d >= 0) atomicAdd(&hist[(unsigned)d / WPS2], 1);
  }
  __syncthreads();
  {  // hist[j] -> global run base (each j owned by thread tid==j)
    int c = hist[tid];
    int base = (c > 0) ? atomicAdd(&bcur2[tid], c) : 0;
    __syncthreads();
    hist[tid] = base;
  }
  __syncthreads();
#pragma unroll
  for (int j = 0; j < EPB; ++j) {
    int d = dv[j];
    if (d < 0) continue;
    int pos = atomicAdd(&hist[(unsigned)d / WPS2], 1);
    srcb[pos] = sv[j];
    dstb[pos] = d;
  }
}

// ---------------------------------------------------------------------------
// Ownership histogram: block b owns dst window [b*WPS2, ...); reads ONLY its
// own sub-bucket edges; LDS counts; plain stores of counts + dinv.
// ---------------------------------------------------------------------------
__global__ __launch_bounds__(256) void k_hist2(const int* __restrict__ dstb,
                                               const int* __restrict__ bcur2,
                                               int* __restrict__ counts,
                                               float* __restrict__ dinv) {
  __shared__ int lc[WPS2];
  const int b = blockIdx.x;
  const int nlo = b * WPS2;
  const int nhi = (nlo + WPS2 < NN) ? nlo + WPS2 : NN;
  const int nw = nhi - nlo;
  for (int j = threadIdx.x; j < nw; j += 256) lc[j] = 0;
  __syncthreads();
  const int cnt = bcur2[b] - b * CAP2;
  const long s0 = (long)b * CAP2;
  for (int i = threadIdx.x; i < cnt; i += 256)
    atomicAdd(&lc[dstb[s0 + i] - nlo], 1);
  __syncthreads();
  for (int j = threadIdx.x; j < nw; j += 256) {
    int c = lc[j];
    counts[nlo + j] = c;
    dinv[nlo + j] = rsqrtf((float)c + 1.0f);  // +1 self-loop
  }
}

// ---------------------------------------------------------------------------
// Ownership scatter: LDS cursors from rowptr; csr writes land in the block's
// ~25KB contiguous window.
// ---------------------------------------------------------------------------
__global__ __launch_bounds__(256) void k_scatter2(const int* __restrict__ dstb,
                                                  const int* __restrict__ srcb,
                                                  const int* __restrict__ bcur2,
                                                  const int* __restrict__ rowptr,
                                                  int* __restrict__ csr) {
  __shared__ int cur[WPS2];
  const int b = blockIdx.x;
  const int nlo = b * WPS2;
  const int nhi = (nlo + WPS2 < NN) ? nlo + WPS2 : NN;
  const int nw = nhi - nlo;
  for (int j = threadIdx.x; j < nw; j += 256) cur[j] = rowptr[nlo + j];
  __syncthreads();
  const int cnt = bcur2[b] - b * CAP2;
  const long s0 = (long)b * CAP2;
  for (int i = threadIdx.x; i < cnt; i += 256) {
    int d = dstb[s0 + i];
    int pos = atomicAdd(&cur[d - nlo], 1);
    csr[pos] = srcb[s0 + i];
  }
}

// ---- 3-kernel exclusive scan of counts[NN] -> rowptr ----------------------
__global__ __launch_bounds__(512) void k_scan1(const int* __restrict__ counts,
                                               int* __restrict__ rowptr,
                                               int* __restrict__ bsum) {
  __shared__ int sm[512];
  int tid = threadIdx.x;
  int i = blockIdx.x * 512 + tid;
  int v = (i < NN) ? counts[i] : 0;
  sm[tid] = v;
  __syncthreads();
  for (int off = 1; off < 512; off <<= 1) {
    int t = (tid >= off) ? sm[tid - off] : 0;
    __syncthreads();
    sm[tid] += t;
    __syncthreads();
  }
  if (i < NN) rowptr[i] = sm[tid] - v;
  if (tid == 511) bsum[blockIdx.x] = sm[tid];
}

__global__ void k_scan2(int* __restrict__ bsum, int nb) {
  if (threadIdx.x == 0 && blockIdx.x == 0) {
    int run = 0;
    for (int b = 0; b < nb; ++b) { int v = bsum[b]; bsum[b] = run; run += v; }
  }
}

__global__ __launch_bounds__(512) void k_scan3(int* __restrict__ rowptr,
                                               const int* __restrict__ bsum, int E) {
  int i = blockIdx.x * 512 + threadIdx.x;
  if (i < NN) rowptr[i] += bsum[blockIdx.x];
  if (i == 0) rowptr[NN] = E;
}

// ---------------------------------------------------------------------------
// W prep: Wt[n][k] fp16 from W[k][n] fp32.
// ---------------------------------------------------------------------------
template <int COUT>
__global__ void k_wprep(const float* __restrict__ W, f16* __restrict__ Wt) {
  int idx = blockIdx.x * 256 + threadIdx.x;
  if (idx < 128 * COUT) {
    int k = idx / COUT, n = idx % COUT;
    Wt[n * 128 + k] = (f16)W[idx];
  }
}

// ---------------------------------------------------------------------------
// MFMA GEMM: hn[row] = ((relu?)X[row] @ W) * dinv[row], fp16 out.
// ---------------------------------------------------------------------------
template <int COUT, bool RELU, typename TIN>
__global__ __launch_bounds__(256) void gemm_mfma(const TIN* __restrict__ X,
                                                 const f16* __restrict__ Wt,
                                                 const float* __restrict__ dinv,
                                                 f16* __restrict__ Y) {
  constexpr int NF = COUT / 16;
  __shared__ f16 Al[128 * 128];
  __shared__ f16 Bl[COUT * 128];
  const int tid = threadIdx.x;
  const long row0 = (long)blockIdx.x * 128;

  for (int c = tid; c < COUT * 16; c += 256) {
    int n = c >> 4, g = c & 15;
    f16x8 v = *(const f16x8*)&Wt[n * 128 + g * 8];
    *(f16x8*)((char*)Bl + n * 256 + ((g * 16) ^ ((n & 7) << 4))) = v;
  }
  for (int c = tid; c < 2048; c += 256) {
    int r = c >> 4, g = c & 15;
    long grow = row0 + r;
    f16x8 v;
    if (grow < NN) {
      if constexpr (sizeof(TIN) == 4) {
        const float4* p = (const float4*)&X[grow * 128 + g * 8];
        float4 p0 = p[0], p1 = p[1];
        float f[8] = {p0.x, p0.y, p0.z, p0.w, p1.x, p1.y, p1.z, p1.w};
#pragma unroll
        for (int j = 0; j < 8; ++j) {
          float t = RELU ? fmaxf(f[j], 0.f) : f[j];
          v[j] = (f16)t;
        }
      } else {
        v = *(const f16x8*)&X[grow * 128 + g * 8];
        if (RELU) {
#pragma unroll
          for (int j = 0; j < 8; ++j) v[j] = v[j] > (f16)0 ? v[j] : (f16)0;
        }
      }
    } else {
#pragma unroll
      for (int j = 0; j < 8; ++j) v[j] = (f16)0;
    }
    *(f16x8*)((char*)Al + r * 256 + ((g * 16) ^ ((r & 7) << 4))) = v;
  }
  __syncthreads();

  const int l = tid & 63, w = tid >> 6;
  const int lm = l & 15, lg = l >> 4;
  const int r0 = w * 32 + lm, r1 = r0 + 16;

  f32x4 acc0[NF], acc1[NF];
#pragma unroll
  for (int nf = 0; nf < NF; ++nf) {
    acc0[nf] = (f32x4)(0.f);
    acc1[nf] = (f32x4)(0.f);
  }

#pragma unroll
  for (int kk = 0; kk < 4; ++kk) {
    const int kb = kk * 64 + lg * 16;
    f16x8 a0 = *(const f16x8*)((const char*)Al + r0 * 256 + (kb ^ ((r0 & 7) << 4)));
    f16x8 a1 = *(const f16x8*)((const char*)Al + r1 * 256 + (kb ^ ((r1 & 7) << 4)));
#pragma unroll
    for (int nf = 0; nf < NF; ++nf) {
      int n = nf * 16 + lm;
      f16x8 b = *(const f16x8*)((const char*)Bl + n * 256 + (kb ^ ((n & 7) << 4)));
      acc0[nf] = __builtin_amdgcn_mfma_f32_16x16x32_f16(a0, b, acc0[nf], 0, 0, 0);
      acc1[nf] = __builtin_amdgcn_mfma_f32_16x16x32_f16(a1, b, acc1[nf], 0, 0, 0);
    }
  }

#pragma unroll
  for (int reg = 0; reg < 4; ++reg) {
    long gr0 = row0 + w * 32 + lg * 4 + reg;
    long gr1 = gr0 + 16;
    float d0 = (gr0 < NN) ? dinv[gr0] : 0.f;
    float d1 = (gr1 < NN) ? dinv[gr1] : 0.f;
#pragma unroll
    for (int nf = 0; nf < NF; ++nf) {
      if (gr0 < NN) Y[gr0 * COUT + nf * 16 + lm] = (f16)(acc0[nf][reg] * d0);
      if (gr1 < NN) Y[gr1 * COUT + nf * 16 + lm] = (f16)(acc1[nf][reg] * d1);
    }
  }
}

// ---------------------------------------------------------------------------
// Gather: out[d] = dinv[d]*(hn[d] + sum_{s in N(d)} hn[s]) + bias.
// ---------------------------------------------------------------------------
template <int C, typename TOUT>
__global__ __launch_bounds__(256) void k_agg_csr(const __half* __restrict__ hn,
                                                 const int* __restrict__ rowptr,
                                                 const int* __restrict__ csr,
                                                 const float* __restrict__ dinv,
                                                 const float* __restrict__ bias,
                                                 TOUT* __restrict__ out) {
  constexpr int TP = C / 8;
  long t = (long)blockIdx.x * 256 + threadIdx.x;
  int d = (int)(t / TP);
  if (d >= NN) return;
  int c8 = (int)(t % TP) * 8;

  float acc[8];
  {
    float4 raw = *(const float4*)&hn[(long)d * C + c8];
    const __half2* h2 = (const __half2*)&raw;
#pragma unroll
    for (int q = 0; q < 4; ++q) {
      float2 f = __half22float2(h2[q]);
      acc[2 * q] = f.x; acc[2 * q + 1] = f.y;
    }
  }
  int e = rowptr[d];
  const int end = rowptr[d + 1];

  for (; e + 4 <= end; e += 4) {
    int s0 = csr[e], s1 = csr[e + 1], s2 = csr[e + 2], s3 = csr[e + 3];
    float4 r0 = *(const float4*)&hn[(long)s0 * C + c8];
    float4 r1 = *(const float4*)&hn[(long)s1 * C + c8];
    float4 r2 = *(const float4*)&hn[(long)s2 * C + c8];
    float4 r3 = *(const float4*)&hn[(long)s3 * C + c8];
    const __half2* a0 = (const __half2*)&r0;
    const __half2* a1 = (const __half2*)&r1;
    const __half2* a2 = (const __half2*)&r2;
    const __half2* a3 = (const __half2*)&r3;
#pragma unroll
    for (int q = 0; q < 4; ++q) {
      float2 f0 = __half22float2(a0[q]);
      float2 f1 = __half22float2(a1[q]);
      float2 f2 = __half22float2(a2[q]);
      float2 f3 = __half22float2(a3[q]);
      acc[2 * q]     += (f0.x + f1.x) + (f2.x + f3.x);
      acc[2 * q + 1] += (f0.y + f1.y) + (f2.y + f3.y);
    }
  }
  for (; e < end; ++e) {
    int s = csr[e];
    float4 r0 = *(const float4*)&hn[(long)s * C + c8];
    const __half2* a0 = (const __half2*)&r0;
#pragma unroll
    for (int q = 0; q < 4; ++q) {
      float2 f0 = __half22float2(a0[q]);
      acc[2 * q] += f0.x; acc[2 * q + 1] += f0.y;
    }
  }

  float dd = dinv[d];
  float4 b0 = *(const float4*)&bias[c8];
  float4 b1 = *(const float4*)&bias[c8 + 4];
  float o[8];
  o[0] = acc[0] * dd + b0.x; o[1] = acc[1] * dd + b0.y;
  o[2] = acc[2] * dd + b0.z; o[3] = acc[3] * dd + b0.w;
  o[4] = acc[4] * dd + b1.x; o[5] = acc[5] * dd + b1.y;
  o[6] = acc[6] * dd + b1.z; o[7] = acc[7] * dd + b1.w;

  if constexpr (sizeof(TOUT) == 2) {
    __half2 hp[4];
    hp[0] = __floats2half2_rn(o[0], o[1]);
    hp[1] = __floats2half2_rn(o[2], o[3]);
    hp[2] = __floats2half2_rn(o[4], o[5]);
    hp[3] = __floats2half2_rn(o[6], o[7]);
    *(float4*)&out[(long)d * C + c8] = *(float4*)hp;
  } else {
    *(float4*)&out[(long)d * C + c8]     = make_float4(o[0], o[1], o[2], o[3]);
    *(float4*)&out[(long)d * C + c8 + 4] = make_float4(o[4], o[5], o[6], o[7]);
  }
}

extern "C" void kernel_launch(void* const* d_in, const int* in_sizes, int n_in,
                              void* d_out, int out_size, void* d_ws, size_t ws_size,
                              hipStream_t stream) {
  const float* x  = (const float*)d_in[0];
  const void*  ep = d_in[1];
  const float* W1 = (const float*)d_in[2];
  const float* b1 = (const float*)d_in[3];
  const float* W2 = (const float*)d_in[4];
  const float* b2 = (const float*)d_in[5];
  float* out = (float*)d_out;
  const int E = in_sizes[1] / 2;

  // workspace layout (int-element offsets from base)
  float*  wsf    = (float*)d_ws;
  int*    wsi    = (int*)d_ws;
  int*    flag   = wsi;                        // [0]
  int*    bcur2  = wsi + 16;                   // 256
  float*  dinv   = wsf + 512;                  // 100000 f
  int*    counts = wsi + 100512;               // 100000
  int*    rowptr = wsi + 200512;               // 100001
  int*    bsum   = wsi + 300544;               // 256
  f16*    Wt1    = (f16*)(wsi + 300800);       // 16384 halves (8192 ints)
  f16*    Wt2    = (f16*)(wsi + 308992);       // 8192 halves (4096 ints)
  int*    csr    = wsi + 313088;               // 1600000
  int*    srcb   = wsi + 1913088;              // 256*CAP2 = 2097152
  int*    dstb   = wsi + 4010240;              // 2097152  (ends 6107392)
  // srcb/dstb dead after k_scatter2 -> hn1/a1 alias that region
  f16*    hn1    = (f16*)(wsi + 1913088);      // 12.8M halves (6.4M ints)
  f16*    a1     = (f16*)(wsi + 8313088);      // 12.8M halves (ends 14713088)
  f16*    hn2    = hn1;                        // hn1 dead once a1 built

  const int NB = (NN + 511) / 512;             // 196
  const int SB = (E + 256 * EPB - 1) / (256 * EPB);  // 391
  const int GB = (NN + 127) / 128;             // 782

  k_detect<<<1, 1024, 0, stream>>>((const unsigned*)ep, flag);
  k_init256<<<1, NSB, 0, stream>>>(bcur2);
  k_wprep<128><<<64, 256, 0, stream>>>(W1, Wt1);
  k_wprep<64><<<32, 256, 0, stream>>>(W2, Wt2);
  k_split<<<SB, 256, 0, stream>>>(ep, flag, E, bcur2, srcb, dstb);
  k_hist2<<<NSB, 256, 0, stream>>>(dstb, bcur2, counts, dinv);
  k_scan1<<<NB, 512, 0, stream>>>(counts, rowptr, bsum);
  k_scan2<<<1, 64, 0, stream>>>(bsum, NB);
  k_scan3<<<NB, 512, 0, stream>>>(rowptr, bsum, E);
  k_scatter2<<<NSB, 256, 0, stream>>>(dstb, srcb, bcur2, rowptr, csr);

  // layer 1
  gemm_mfma<128, false, float><<<GB, 256, 0, stream>>>(x, Wt1, dinv, hn1);
  k_agg_csr<128, __half><<<(NN * 16) / 256, 256, 0, stream>>>(
      (const __half*)hn1, rowptr, csr, dinv, b1, (__half*)a1);

  // layer 2 (relu fused into staging conversion)
  gemm_mfma<64, true, f16><<<GB, 256, 0, stream>>>(a1, Wt2, dinv, hn2);
  k_agg_csr<64, float><<<(NN * 8) / 256, 256, 0, stream>>>(
      (const __half*)hn2, rowptr, csr, dinv, b2, out);
}

// Round 7
// 193.475 us; speedup vs baseline: 2.3903x; 1.1655x over previous
//
#include <hip/hip_runtime.h>
#include <hip/hip_fp16.h>

#define NN 100000
#define NSB 256            // dst windows (one ownership block each)
#define WPS2 391           // dst nodes per window (ceil(NN/NSB))
#define CAP2 8192          // edge capacity per window (mean 6256)
#define EPB 16             // edges per thread in split

typedef _Float16 f16;
typedef _Float16 f16x8 __attribute__((ext_vector_type(8)));
typedef float f32x4 __attribute__((ext_vector_type(4)));

__device__ __forceinline__ int eload(const void* e, long i, int is64) {
  if (is64) return (int)((const long long*)e)[i];
  return ((const int*)e)[i];
}

// detect int32/int64 (odd words zero => int64) + init bcur2
__global__ __launch_bounds__(1024) void k_detect(const unsigned* __restrict__ e,
                                                 int* __restrict__ flag,
                                                 int* __restrict__ bcur2) {
  __shared__ unsigned red[1024];
  int t = threadIdx.x;
  if (t < NSB) bcur2[t] = t * CAP2;
  unsigned acc = e[1 + 2 * t] | e[1 + 2 * t + 2048];
  red[t] = acc;
  __syncthreads();
  for (int off = 512; off > 0; off >>= 1) {
    if (t < off) red[t] |= red[t + off];
    __syncthreads();
  }
  if (t == 0) *flag = (red[0] == 0) ? 1 : 0;  // 1 => int64
}

// both weights: Wt[n][k] fp16 from W[k][n] fp32
__global__ void k_wprep(const float* __restrict__ W1, const float* __restrict__ W2,
                        f16* __restrict__ Wt1, f16* __restrict__ Wt2) {
  int idx = blockIdx.x * 256 + threadIdx.x;
  if (idx < 128 * 128) {
    int k = idx / 128, n = idx % 128;
    Wt1[n * 128 + k] = (f16)W1[idx];
  } else {
    int i2 = idx - 128 * 128;
    if (i2 < 128 * 64) {
      int k = i2 / 64, n = i2 % 64;
      Wt2[n * 128 + k] = (f16)W2[i2];
    }
  }
}

// ---------------------------------------------------------------------------
// 256-way multi-split by dst window (SoA srcb/dstb, contiguous runs).
// ---------------------------------------------------------------------------
__global__ __launch_bounds__(256) void k_split(const void* __restrict__ e,
                                               const int* __restrict__ flag,
                                               int E, int* __restrict__ bcur2,
                                               int* __restrict__ srcb,
                                               int* __restrict__ dstb) {
  __shared__ int hist[NSB];
  const int tid = threadIdx.x;
  const long b0 = (long)blockIdx.x * (256 * EPB);
  const int is64 = *flag;
  hist[tid] = 0;
  __syncthreads();

  int sv[EPB], dv[EPB];
#pragma unroll
  for (int j = 0; j < EPB; ++j) {
    long idx = b0 + j * 256 + tid;
    int s = 0, d = -1;
    if (idx < E) {
      s = eload(e, idx, is64);
      d = eload(e, (long)E + idx, is64);
    }
    sv[j] = s; dv[j] = d;
    if (d >= 0) atomicAdd(&hist[(unsigned)d / WPS2], 1);
  }
  __syncthreads();
  {
    int c = hist[tid];
    int base = (c > 0) ? atomicAdd(&bcur2[tid], c) : 0;
    __syncthreads();
    hist[tid] = base;
  }
  __syncthreads();
#pragma unroll
  for (int j = 0; j < EPB; ++j) {
    int d = dv[j];
    if (d < 0) continue;
    int pos = atomicAdd(&hist[(unsigned)d / WPS2], 1);
    srcb[pos] = sv[j];
    dstb[pos] = d;
  }
}

// scan of 256 window totals (known from bcur2) -> wbase; rowptr[NN]=E
__global__ __launch_bounds__(256) void k_wscan(const int* __restrict__ bcur2,
                                               int* __restrict__ wbase,
                                               int* __restrict__ rowptr, int E) {
  __shared__ int sm[NSB];
  int t = threadIdx.x;
  int c = bcur2[t] - t * CAP2;
  sm[t] = c;
  __syncthreads();
  for (int off = 1; off < NSB; off <<= 1) {
    int a = (t >= off) ? sm[t - off] : 0;
    __syncthreads();
    sm[t] += a;
    __syncthreads();
  }
  wbase[t] = sm[t] - c;
  if (t == 0) rowptr[NN] = E;
}

// ---------------------------------------------------------------------------
// Fused per-window build: LDS hist -> LDS scan -> rowptr+dinv stores ->
// csr replay via LDS cursors. Block b owns dst window [b*WPS2, ...).
// ---------------------------------------------------------------------------
__global__ __launch_bounds__(256) void k_build(const int* __restrict__ dstb,
                                               const int* __restrict__ srcb,
                                               const int* __restrict__ bcur2,
                                               const int* __restrict__ wbase,
                                               int* __restrict__ rowptr,
                                               float* __restrict__ dinv,
                                               int* __restrict__ csr) {
  __shared__ int lc[512];
  __shared__ int cur[512];
  const int tid = threadIdx.x;
  const int b = blockIdx.x;
  const int nlo = b * WPS2;
  const int nhi = (nlo + WPS2 < NN) ? nlo + WPS2 : NN;
  const int nw = nhi - nlo;
  lc[tid] = 0; lc[tid + 256] = 0;
  __syncthreads();
  const int cnt = bcur2[b] - b * CAP2;
  const long s0 = (long)b * CAP2;
  for (int i = tid; i < cnt; i += 256)
    atomicAdd(&lc[dstb[s0 + i] - nlo], 1);
  __syncthreads();
  // inclusive Hillis-Steele over 512 (2 elems/thread)
  for (int off = 1; off < 512; off <<= 1) {
    int a0 = (tid >= off) ? lc[tid - off] : 0;
    int a1 = (tid + 256 >= off) ? lc[tid + 256 - off] : 0;
    __syncthreads();
    lc[tid] += a0; lc[tid + 256] += a1;
    __syncthreads();
  }
  const int wb = wbase[b];
#pragma unroll
  for (int h = 0; h < 2; ++h) {
    int j = tid + h * 256;
    if (j < nw) {
      int inc = lc[j];
      int c = inc - (j > 0 ? lc[j - 1] : 0);
      int ex = wb + inc - c;
      rowptr[nlo + j] = ex;
      dinv[nlo + j] = rsqrtf((float)c + 1.0f);  // +1 self-loop
      cur[j] = ex;
    }
  }
  __syncthreads();
  for (int i = tid; i < cnt; i += 256) {
    int d = dstb[s0 + i];
    int pos = atomicAdd(&cur[d - nlo], 1);
    csr[pos] = srcb[s0 + i];
  }
}

// ---------------------------------------------------------------------------
// MFMA GEMM (layer 1): hn[row] = (X[row] @ W1) * dinv[row], fp16 out.
// ---------------------------------------------------------------------------
__global__ __launch_bounds__(256) void gemm_mfma(const float* __restrict__ X,
                                                 const f16* __restrict__ Wt,
                                                 const float* __restrict__ dinv,
                                                 f16* __restrict__ Y) {
  constexpr int NF = 8;  // COUT=128
  __shared__ f16 Al[128 * 128];
  __shared__ f16 Bl[128 * 128];
  const int tid = threadIdx.x;
  const long row0 = (long)blockIdx.x * 128;

  for (int c = tid; c < 128 * 16; c += 256) {
    int n = c >> 4, g = c & 15;
    f16x8 v = *(const f16x8*)&Wt[n * 128 + g * 8];
    *(f16x8*)((char*)Bl + n * 256 + ((g * 16) ^ ((n & 7) << 4))) = v;
  }
  for (int c = tid; c < 2048; c += 256) {
    int r = c >> 4, g = c & 15;
    long grow = row0 + r;
    f16x8 v;
    if (grow < NN) {
      const float4* p = (const float4*)&X[grow * 128 + g * 8];
      float4 p0 = p[0], p1 = p[1];
      float f[8] = {p0.x, p0.y, p0.z, p0.w, p1.x, p1.y, p1.z, p1.w};
#pragma unroll
      for (int j = 0; j < 8; ++j) v[j] = (f16)f[j];
    } else {
#pragma unroll
      for (int j = 0; j < 8; ++j) v[j] = (f16)0;
    }
    *(f16x8*)((char*)Al + r * 256 + ((g * 16) ^ ((r & 7) << 4))) = v;
  }
  __syncthreads();

  const int l = tid & 63, w = tid >> 6;
  const int lm = l & 15, lg = l >> 4;
  const int r0 = w * 32 + lm, r1 = r0 + 16;

  f32x4 acc0[NF], acc1[NF];
#pragma unroll
  for (int nf = 0; nf < NF; ++nf) { acc0[nf] = (f32x4)(0.f); acc1[nf] = (f32x4)(0.f); }

#pragma unroll
  for (int kk = 0; kk < 4; ++kk) {
    const int kb = kk * 64 + lg * 16;
    f16x8 a0 = *(const f16x8*)((const char*)Al + r0 * 256 + (kb ^ ((r0 & 7) << 4)));
    f16x8 a1 = *(const f16x8*)((const char*)Al + r1 * 256 + (kb ^ ((r1 & 7) << 4)));
#pragma unroll
    for (int nf = 0; nf < NF; ++nf) {
      int n = nf * 16 + lm;
      f16x8 b = *(const f16x8*)((const char*)Bl + n * 256 + (kb ^ ((n & 7) << 4)));
      acc0[nf] = __builtin_amdgcn_mfma_f32_16x16x32_f16(a0, b, acc0[nf], 0, 0, 0);
      acc1[nf] = __builtin_amdgcn_mfma_f32_16x16x32_f16(a1, b, acc1[nf], 0, 0, 0);
    }
  }

#pragma unroll
  for (int reg = 0; reg < 4; ++reg) {
    long gr0 = row0 + w * 32 + lg * 4 + reg;
    long gr1 = gr0 + 16;
    float d0 = (gr0 < NN) ? dinv[gr0] : 0.f;
    float d1 = (gr1 < NN) ? dinv[gr1] : 0.f;
#pragma unroll
    for (int nf = 0; nf < NF; ++nf) {
      if (gr0 < NN) Y[gr0 * 128 + nf * 16 + lm] = (f16)(acc0[nf][reg] * d0);
      if (gr1 < NN) Y[gr1 * 128 + nf * 16 + lm] = (f16)(acc1[nf][reg] * d1);
    }
  }
}

// ---------------------------------------------------------------------------
// Fused agg1 + gemm2: block owns 64 dst rows. Staging phase aggregates
// a1[r] = relu(dinv*(hn1[r] + gather) + b1) -> fp16 swizzled LDS A-tile;
// then MFMA with W2; epilogue *dinv -> hn2 (fp16).
// LDS 32KB -> 5 blocks/CU keeps gather concurrency high.
// ---------------------------------------------------------------------------
__global__ __launch_bounds__(256) void k_aggemm(const f16* __restrict__ hn1,
                                                const int* __restrict__ rowptr,
                                                const int* __restrict__ csr,
                                                const float* __restrict__ dinv,
                                                const float* __restrict__ b1,
                                                const f16* __restrict__ Wt2,
                                                f16* __restrict__ hn2) {
  __shared__ f16 Al[64 * 128];   // 16KB
  __shared__ f16 Bl[64 * 128];   // 16KB
  const int tid = threadIdx.x;
  const long row0 = (long)blockIdx.x * 64;

  for (int c = tid; c < 64 * 16; c += 256) {
    int n = c >> 4, g = c & 15;
    f16x8 v = *(const f16x8*)&Wt2[n * 128 + g * 8];
    *(f16x8*)((char*)Bl + n * 256 + ((g * 16) ^ ((n & 7) << 4))) = v;
  }

  const int g = tid & 15;        // channel chunk (8 ch)
  const int c8 = g * 8;
  const int rloc = tid >> 4;     // 0..15
  float4 bb0 = *(const float4*)&b1[c8];
  float4 bb1 = *(const float4*)&b1[c8 + 4];
  const float bb[8] = {bb0.x, bb0.y, bb0.z, bb0.w, bb1.x, bb1.y, bb1.z, bb1.w};

#pragma unroll
  for (int p = 0; p < 4; ++p) {
    int r = p * 16 + rloc;
    long dd = row0 + r;
    f16x8 v;
    if (dd < NN) {
      float acc[8];
      f16x8 sv = *(const f16x8*)&hn1[dd * 128 + c8];
#pragma unroll
      for (int j = 0; j < 8; ++j) acc[j] = (float)sv[j];
      int e = rowptr[dd];
      const int end = rowptr[dd + 1];
      for (; e + 4 <= end; e += 4) {
        int s0 = csr[e], s1 = csr[e + 1], s2 = csr[e + 2], s3 = csr[e + 3];
        f16x8 v0 = *(const f16x8*)&hn1[(long)s0 * 128 + c8];
        f16x8 v1 = *(const f16x8*)&hn1[(long)s1 * 128 + c8];
        f16x8 v2 = *(const f16x8*)&hn1[(long)s2 * 128 + c8];
        f16x8 v3 = *(const f16x8*)&hn1[(long)s3 * 128 + c8];
#pragma unroll
        for (int j = 0; j < 8; ++j)
          acc[j] += ((float)v0[j] + (float)v1[j]) + ((float)v2[j] + (float)v3[j]);
      }
      for (; e < end; ++e) {
        int s = csr[e];
        f16x8 v0 = *(const f16x8*)&hn1[(long)s * 128 + c8];
#pragma unroll
        for (int j = 0; j < 8; ++j) acc[j] += (float)v0[j];
      }
      float ddv = dinv[dd];
#pragma unroll
      for (int j = 0; j < 8; ++j) {
        float t = fmaxf(acc[j] * ddv + bb[j], 0.f);
        v[j] = (f16)t;
      }
    } else {
#pragma unroll
      for (int j = 0; j < 8; ++j) v[j] = (f16)0;
    }
    *(f16x8*)((char*)Al + r * 256 + ((g * 16) ^ ((r & 7) << 4))) = v;
  }
  __syncthreads();

  // MFMA: 4 waves, wave w owns rows w*16..w*16+15; COUT=64 (NF=4)
  const int l = tid & 63, w = tid >> 6;
  const int lm = l & 15, lg = l >> 4;
  const int r0 = w * 16 + lm;

  f32x4 acc0[4];
#pragma unroll
  for (int nf = 0; nf < 4; ++nf) acc0[nf] = (f32x4)(0.f);

#pragma unroll
  for (int kk = 0; kk < 4; ++kk) {
    const int kb = kk * 64 + lg * 16;
    f16x8 a0 = *(const f16x8*)((const char*)Al + r0 * 256 + (kb ^ ((r0 & 7) << 4)));
#pragma unroll
    for (int nf = 0; nf < 4; ++nf) {
      int n = nf * 16 + lm;
      f16x8 b = *(const f16x8*)((const char*)Bl + n * 256 + (kb ^ ((n & 7) << 4)));
      acc0[nf] = __builtin_amdgcn_mfma_f32_16x16x32_f16(a0, b, acc0[nf], 0, 0, 0);
    }
  }

#pragma unroll
  for (int reg = 0; reg < 4; ++reg) {
    long gr0 = row0 + w * 16 + lg * 4 + reg;
    if (gr0 < NN) {
      float d0 = dinv[gr0];
#pragma unroll
      for (int nf = 0; nf < 4; ++nf)
        hn2[gr0 * 64 + nf * 16 + lm] = (f16)(acc0[nf][reg] * d0);
    }
  }
}

// ---------------------------------------------------------------------------
// Gather agg (layer 2): out[d] = dinv[d]*(hn[d] + sum hn[s]) + b2, fp32 out.
// ---------------------------------------------------------------------------
__global__ __launch_bounds__(256) void k_agg2(const __half* __restrict__ hn,
                                              const int* __restrict__ rowptr,
                                              const int* __restrict__ csr,
                                              const float* __restrict__ dinv,
                                              const float* __restrict__ bias,
                                              float* __restrict__ out) {
  constexpr int C = 64, TP = 8;
  long t = (long)blockIdx.x * 256 + threadIdx.x;
  int d = (int)(t / TP);
  if (d >= NN) return;
  int c8 = (int)(t % TP) * 8;

  float acc[8];
  {
    float4 raw = *(const float4*)&hn[(long)d * C + c8];
    const __half2* h2 = (const __half2*)&raw;
#pragma unroll
    for (int q = 0; q < 4; ++q) {
      float2 f = __half22float2(h2[q]);
      acc[2 * q] = f.x; acc[2 * q + 1] = f.y;
    }
  }
  int e = rowptr[d];
  const int end = rowptr[d + 1];

  for (; e + 8 <= end; e += 8) {
    float4 r[8];
#pragma unroll
    for (int u = 0; u < 8; ++u) r[u] = *(const float4*)&hn[(long)csr[e + u] * C + c8];
#pragma unroll
    for (int u = 0; u < 8; ++u) {
      const __half2* a0 = (const __half2*)&r[u];
#pragma unroll
      for (int q = 0; q < 4; ++q) {
        float2 f0 = __half22float2(a0[q]);
        acc[2 * q] += f0.x; acc[2 * q + 1] += f0.y;
      }
    }
  }
  for (; e + 4 <= end; e += 4) {
    float4 r[4];
#pragma unroll
    for (int u = 0; u < 4; ++u) r[u] = *(const float4*)&hn[(long)csr[e + u] * C + c8];
#pragma unroll
    for (int u = 0; u < 4; ++u) {
      const __half2* a0 = (const __half2*)&r[u];
#pragma unroll
      for (int q = 0; q < 4; ++q) {
        float2 f0 = __half22float2(a0[q]);
        acc[2 * q] += f0.x; acc[2 * q + 1] += f0.y;
      }
    }
  }
  for (; e < end; ++e) {
    float4 r0 = *(const float4*)&hn[(long)csr[e] * C + c8];
    const __half2* a0 = (const __half2*)&r0;
#pragma unroll
    for (int q = 0; q < 4; ++q) {
      float2 f0 = __half22float2(a0[q]);
      acc[2 * q] += f0.x; acc[2 * q + 1] += f0.y;
    }
  }

  float dd = dinv[d];
  float4 b0 = *(const float4*)&bias[c8];
  float4 b1 = *(const float4*)&bias[c8 + 4];
  *(float4*)&out[(long)d * C + c8] =
      make_float4(acc[0] * dd + b0.x, acc[1] * dd + b0.y,
                  acc[2] * dd + b0.z, acc[3] * dd + b0.w);
  *(float4*)&out[(long)d * C + c8 + 4] =
      make_float4(acc[4] * dd + b1.x, acc[5] * dd + b1.y,
                  acc[6] * dd + b1.z, acc[7] * dd + b1.w);
}

extern "C" void kernel_launch(void* const* d_in, const int* in_sizes, int n_in,
                              void* d_out, int out_size, void* d_ws, size_t ws_size,
                              hipStream_t stream) {
  const float* x  = (const float*)d_in[0];
  const void*  ep = d_in[1];
  const float* W1 = (const float*)d_in[2];
  const float* b1 = (const float*)d_in[3];
  const float* W2 = (const float*)d_in[4];
  const float* b2 = (const float*)d_in[5];
  float* out = (float*)d_out;
  const int E = in_sizes[1] / 2;

  // workspace layout (int-element offsets)
  float*  wsf    = (float*)d_ws;
  int*    wsi    = (int*)d_ws;
  int*    flag   = wsi;                        // [0]
  int*    bcur2  = wsi + 64;                   // 256
  int*    wbase  = wsi + 320;                  // 256
  float*  dinv   = wsf + 576;                  // 100000
  int*    rowptr = wsi + 100576;               // 100001 (ends 200577)
  f16*    Wt1    = (f16*)(wsi + 200640);       // 16384 halves
  f16*    Wt2    = (f16*)(wsi + 208832);       // 8192 halves
  int*    csr    = wsi + 212992;               // 1600000
  int*    srcb   = wsi + 1812992;              // 2097152
  int*    dstb   = wsi + 3910144;              // 2097152
  f16*    hn1    = (f16*)(wsi + 6007296);      // 12.8M halves
  f16*    hn2    = (f16*)(wsi + 12407296);     // 6.4M halves used

  const int SB = (E + 256 * EPB - 1) / (256 * EPB);  // 391
  const int GB = (NN + 127) / 128;                   // 782
  const int FB = (NN + 63) / 64;                     // 1563

  k_detect<<<1, 1024, 0, stream>>>((const unsigned*)ep, flag, bcur2);
  k_wprep<<<96, 256, 0, stream>>>(W1, W2, Wt1, Wt2);
  k_split<<<SB, 256, 0, stream>>>(ep, flag, E, bcur2, srcb, dstb);
  k_wscan<<<1, 256, 0, stream>>>(bcur2, wbase, rowptr, E);
  k_build<<<NSB, 256, 0, stream>>>(dstb, srcb, bcur2, wbase, rowptr, dinv, csr);

  // layer 1 GEMM: hn1 = (x @ W1) * dinv
  gemm_mfma<<<GB, 256, 0, stream>>>(x, Wt1, dinv, hn1);
  // fused agg1 + layer-2 GEMM: hn2 = (relu(agg(hn1)+b1) @ W2) * dinv
  k_aggemm<<<FB, 256, 0, stream>>>(hn1, rowptr, csr, dinv, b1, Wt2, hn2);
  // layer 2 aggregation -> out
  k_agg2<<<(NN * 8 + 255) / 256, 256, 0, stream>>>(
      (const __half*)hn2, rowptr, csr, dinv, b2, out);
}